// Round 7
// baseline (102.268 us; speedup 1.0000x reference)
//
#include <hip/hip_runtime.h>
#include <math.h>

#define SS 2048
#define OSQ 512
#define GG 5
#define NBLK 256

typedef unsigned short u16;
typedef unsigned int u32;
typedef __attribute__((ext_vector_type(8))) short s16x8;
typedef __attribute__((ext_vector_type(4))) float v4f;
typedef __attribute__((ext_vector_type(16))) float v16f;

__device__ __forceinline__ float rcp_f(float x) {
    float r; asm("v_rcp_f32 %0, %1" : "=v"(r) : "v"(x)); return r;
}
__device__ __forceinline__ float cos_rev(float x) {
    float fr, c;
    asm("v_fract_f32 %0, %1" : "=v"(fr) : "v"(x));
    asm("v_cos_f32 %0, %1" : "=v"(c) : "v"(fr));
    return c;
}
__device__ __forceinline__ float cos01(float x) {
    float c; asm("v_cos_f32 %0, %1" : "=v"(c) : "v"(x)); return c;
}
__device__ __forceinline__ u16 f2bf(float f) {
    u32 u = __float_as_uint(f);
    return (u16)((u + 0x7FFFu + ((u >> 16) & 1u)) >> 16);
}
__device__ __forceinline__ float bf2f(u16 h) {
    return __uint_as_float((u32)h << 16);
}
__device__ __forceinline__ void gload16(const void* g, void* l) {
    __builtin_amdgcn_global_load_lds((const __attribute__((address_space(1))) void*)g,
                                     (__attribute__((address_space(3))) void*)l, 16, 0, 0);
}

// ---------------------------------------------------------------------------
// Fragment layouts (16B per lane-slot, bf16):
//   Lt_frag[(o32blk*128 + ks)*64 + slot] : Linker[k][o],
//       o = o32blk*32 + (slot&31), k = ks*16 + (slot>>5)*8 + {0..7}
//   Vt_frag[((b*2+i32blk)*128 + ks)*64 + slot] : V[b][i][k], same slot rule.
// Exactly the A/B operand fragments of v_mfma_f32_32x32x16_bf16.
// ---------------------------------------------------------------------------

union SharedU {
    struct {
        u16 SEQb[64 * 64];        // bf16, swizzled by (row&7)
        u16 Mb[64 * 64];          // bf16, swizzled by (o&7)
        u16 SZb[64 * 64];         // Z bf16, swizzled by batch
        float Z0l[64 * 68];       // pre-LN projection, f32
        u32 Ta32[8 * 2 * 64 * 5]; // T partials bf16 [kc][h][i][10 u16]
    } f;                          // 62.4 KB (phase A)
    struct {
        u16 LB[8][2][2][2048];    // [wave][buf][A/B] 4KB each = 128 KB (phase C)
    } g;
};

// Single persistent kernel: grid 256 x 512, 1 block/CU (128KB LDS), all
// blocks co-resident -> device-scope spin barrier between phases.
__global__ __launch_bounds__(512, 1) void kFused(const float* __restrict__ seq,
                                                 const float* __restrict__ Mm,
                                                 const float* __restrict__ P,
                                                 const float* __restrict__ gamma,
                                                 const float* __restrict__ beta,
                                                 const float* __restrict__ Lnk,
                                                 u16* __restrict__ Lt,
                                                 u16* __restrict__ Vt,
                                                 u32* __restrict__ cnt,
                                                 float* __restrict__ out) {
    __shared__ __align__(16) SharedU S;

    const int t = threadIdx.x;
    const int l = t & 63;
    const int w = t >> 6;

    // ================= PHASE A: produce Lt + Vt (k-block = blockIdx.x) ======
    {
        const int bidA = blockIdx.x;
        const int k0 = bidA * 8;
        const float kf0 = (float)k0;

        const int h = w >> 2;                 // j-half
        const int i0 = (w & 3) * 16;
        const int i_w = i0 + (l & 15);
        const int jc_w = h * 4 + (l >> 4);    // 8-j chunk 0..7

        float pr[40];
        {
            const float4* P4 = (const float4*)(P + ((size_t)i_w * 64 + jc_w * 8) * 5);
            #pragma unroll
            for (int q = 0; q < 10; ++q) {
                float4 v = P4[q];
                pr[q * 4 + 0] = v.x; pr[q * 4 + 1] = v.y; pr[q * 4 + 2] = v.z; pr[q * 4 + 3] = v.w;
            }
        }

        // Lt source loads: issue early, consume at end of phase A.
        float lnv[8];
        #pragma unroll
        for (int j = 0; j < 8; ++j)
            lnv[j] = Lnk[(size_t)(k0 + j) * OSQ + t];

        // stage seq, M as bf16 (swizzled)
        {
            int row = t >> 3, ch = t & 7;
            int b = row >> 3, kq = row & 7;
            const float* sp = &seq[((size_t)b * SS + k0 + kq) * 64 + ch * 8];
            float4 a = *(const float4*)sp, bb4 = *(const float4*)(sp + 4);
            uint4 pk;
            pk.x = (u32)f2bf(a.x) | ((u32)f2bf(a.y) << 16);
            pk.y = (u32)f2bf(a.z) | ((u32)f2bf(a.w) << 16);
            pk.z = (u32)f2bf(bb4.x) | ((u32)f2bf(bb4.y) << 16);
            pk.w = (u32)f2bf(bb4.z) | ((u32)f2bf(bb4.w) << 16);
            *(uint4*)&S.f.SEQb[row * 64 + ((ch ^ (row & 7)) * 8)] = pk;

            const float* mp = &Mm[(size_t)row * 64 + ch * 8];
            float4 c = *(const float4*)mp, d = *(const float4*)(mp + 4);
            uint4 pm;
            pm.x = (u32)f2bf(c.x) | ((u32)f2bf(c.y) << 16);
            pm.y = (u32)f2bf(c.z) | ((u32)f2bf(c.w) << 16);
            pm.z = (u32)f2bf(d.x) | ((u32)f2bf(d.y) << 16);
            pm.w = (u32)f2bf(d.z) | ((u32)f2bf(d.w) << 16);
            *(uint4*)&S.f.Mb[row * 64 + ((ch ^ (row & 7)) * 8)] = pm;
        }

        // cosine recurrence init (trans pipe; overlaps staging + Lnk loads)
        float c0[40], c1[40], t2c[40];
        #pragma unroll
        for (int m = 0; m < 8; ++m) {
            #pragma unroll
            for (int g = 0; g < GG; ++g) {
                int idx = m * 5 + g;
                float pf = (float)((i_w * 64 + jc_w * 8 + m) * 5 + g + 2);
                float inv = rcp_f(pf);
                c0[idx] = cos_rev(kf0 * inv);
                c1[idx] = cos_rev((kf0 + 1.0f) * inv);
                float ct = cos01(inv);
                t2c[idx] = ct + ct;
            }
        }

        float gm[8], bt[8];
        {
            int oc = t & 7;
            float4 a = *(const float4*)&gamma[oc * 8], b = *(const float4*)&gamma[oc * 8 + 4];
            float4 c = *(const float4*)&beta[oc * 8],  d = *(const float4*)&beta[oc * 8 + 4];
            gm[0]=a.x; gm[1]=a.y; gm[2]=a.z; gm[3]=a.w; gm[4]=b.x; gm[5]=b.y; gm[6]=b.z; gm[7]=b.w;
            bt[0]=c.x; bt[1]=c.y; bt[2]=c.z; bt[3]=c.w; bt[4]=d.x; bt[5]=d.y; bt[6]=d.z; bt[7]=d.w;
        }
        __syncthreads();

        // Z0 = seq @ M^T via mfma_32x32x16 (waves 0-3)
        if (w < 4) {
            const int qr = w & 1, qc = w >> 1;
            v16f acc = {0,0,0,0,0,0,0,0,0,0,0,0,0,0,0,0};
            const int rowA = qr * 32 + (l & 31);
            const int rowB = qc * 32 + (l & 31);
            #pragma unroll
            for (int ks = 0; ks < 4; ++ks) {
                int cA = (ks * 2 + (l >> 5)) ^ (rowA & 7);
                int cB = (ks * 2 + (l >> 5)) ^ (rowB & 7);
                s16x8 af = *(const s16x8*)&S.f.SEQb[rowA * 64 + cA * 8];
                s16x8 bf = *(const s16x8*)&S.f.Mb[rowB * 64 + cB * 8];
                acc = __builtin_amdgcn_mfma_f32_32x32x16_bf16(af, bf, acc, 0, 0, 0);
            }
            #pragma unroll
            for (int q = 0; q < 16; ++q) {
                int row = qr * 32 + (q & 3) + 8 * (q >> 2) + 4 * (l >> 5);
                int col = qc * 32 + (l & 31);
                S.f.Z0l[row * 68 + col] = acc[q];
            }
        }
        __syncthreads();

        // LayerNorm -> SZb bf16
        {
            const int rI = t >> 3, oc = t & 7;
            float z0v[8];
            float4 a = *(const float4*)&S.f.Z0l[rI * 68 + oc * 8];
            float4 b = *(const float4*)&S.f.Z0l[rI * 68 + oc * 8 + 4];
            z0v[0]=a.x; z0v[1]=a.y; z0v[2]=a.z; z0v[3]=a.w; z0v[4]=b.x; z0v[5]=b.y; z0v[6]=b.z; z0v[7]=b.w;
            float s1 = ((z0v[0]+z0v[1])+(z0v[2]+z0v[3])) + ((z0v[4]+z0v[5])+(z0v[6]+z0v[7]));
            s1 += __shfl_xor(s1, 1); s1 += __shfl_xor(s1, 2); s1 += __shfl_xor(s1, 4);
            float mu = s1 * 0.015625f;
            float sq = 0.f;
            #pragma unroll
            for (int m = 0; m < 8; ++m) { float dv = z0v[m] - mu; sq = fmaf(dv, dv, sq); }
            sq += __shfl_xor(sq, 1); sq += __shfl_xor(sq, 2); sq += __shfl_xor(sq, 4);
            float rstd = rsqrtf(sq * 0.015625f + 1e-5f);
            u16 zb[8];
            #pragma unroll
            for (int m = 0; m < 8; ++m)
                zb[m] = f2bf(fmaf((z0v[m] - mu) * rstd, gm[m], bt[m]));
            uint4 pk;
            pk.x = (u32)zb[0] | ((u32)zb[1] << 16);
            pk.y = (u32)zb[2] | ((u32)zb[3] << 16);
            pk.z = (u32)zb[4] | ((u32)zb[5] << 16);
            pk.w = (u32)zb[6] | ((u32)zb[7] << 16);
            int slot = oc ^ ((rI >> 3) & 7);
            *(uint4*)&S.f.SZb[rI * 64 + slot * 8] = pk;
        }
        __syncthreads();

        // per-k: W via recurrence -> T via mfma_16x16x32 (no barriers inside)
        const int bcl = l & 7;
        #pragma unroll
        for (int kc = 0; kc < 8; ++kc) {
            if (kc >= 2) {
                #pragma unroll
                for (int x = 0; x < 40; ++x) {
                    float cn = fmaf(t2c[x], c1[x], -c0[x]);
                    c0[x] = c1[x]; c1[x] = cn;
                }
            }
            s16x8 bw;
            #pragma unroll
            for (int j = 0; j < 8; ++j) {
                float a = 0.f;
                #pragma unroll
                for (int g = 0; g < GG; ++g) {
                    float ph = (kc == 0) ? c0[j * 5 + g] : c1[j * 5 + g];
                    a = fmaf(pr[j * 5 + g], ph, a);
                }
                bw[j] = (short)f2bf(a);
            }
            int arow = bcl * 8 + kc;
            int slot = (h * 4 + (l >> 4)) ^ bcl;
            s16x8 az = *(const s16x8*)&S.f.SZb[arow * 64 + slot * 8];
            v4f zc = {0.f, 0.f, 0.f, 0.f};
            v4f d = __builtin_amdgcn_mfma_f32_16x16x32_bf16(az, bw, zc, 0, 0, 0);
            if (l < 32) {
                int ii = i0 + (l & 15);
                int bb2 = (l >> 4) * 2;
                u32 base = (u32)((kc * 2 + h) * 64 + ii) * 5 + bb2;
                S.f.Ta32[base]     = (u32)f2bf(d[0]) | ((u32)f2bf(d[1]) << 16);
                S.f.Ta32[base + 1] = (u32)f2bf(d[2]) | ((u32)f2bf(d[3]) << 16);
            }
        }
        __syncthreads();

        // assembly: thread (w=b, l=i): V = T(h0)+T(h1)+Z0, write Vt fragment
        {
            const u16* TaR = (const u16*)S.f.Ta32;
            float vk[8];
            #pragma unroll
            for (int kc = 0; kc < 8; ++kc)
                vk[kc] = bf2f(TaR[((kc * 2 + 0) * 64 + l) * 10 + w])
                       + bf2f(TaR[((kc * 2 + 1) * 64 + l) * 10 + w])
                       + S.f.Z0l[(w * 8 + kc) * 68 + l];
            uint4 pk;
            pk.x = (u32)f2bf(vk[0]) | ((u32)f2bf(vk[1]) << 16);
            pk.y = (u32)f2bf(vk[2]) | ((u32)f2bf(vk[3]) << 16);
            pk.z = (u32)f2bf(vk[4]) | ((u32)f2bf(vk[5]) << 16);
            pk.w = (u32)f2bf(vk[6]) | ((u32)f2bf(vk[7]) << 16);
            const int ks = k0 >> 4;
            const int hi = (k0 >> 3) & 1;
            size_t idx16 = ((size_t)(w * 2 + (l >> 5)) * 128 + ks) * 64 + (l & 31) + 32 * hi;
            *(uint4*)&Vt[idx16 * 8] = pk;
        }

        // Lt emission (this block's k-slice, all 512 threads; og = t)
        {
            uint4 pk;
            pk.x = (u32)f2bf(lnv[0]) | ((u32)f2bf(lnv[1]) << 16);
            pk.y = (u32)f2bf(lnv[2]) | ((u32)f2bf(lnv[3]) << 16);
            pk.z = (u32)f2bf(lnv[4]) | ((u32)f2bf(lnv[5]) << 16);
            pk.w = (u32)f2bf(lnv[6]) | ((u32)f2bf(lnv[7]) << 16);
            const int ks = k0 >> 4;
            const int hi = (k0 >> 3) & 1;
            size_t idx16 = ((size_t)(t >> 5) * 128 + ks) * 64 + (t & 31) + 32 * hi;
            *(uint4*)&Lt[idx16 * 8] = pk;
        }
    }

    // ================= GRID BARRIER (device-scope) ==========================
    __threadfence();
    __syncthreads();
    if (t == 0) {
        __hip_atomic_fetch_add(cnt, 1u, __ATOMIC_ACQ_REL, __HIP_MEMORY_SCOPE_AGENT);
        while (__hip_atomic_load(cnt, __ATOMIC_ACQUIRE, __HIP_MEMORY_SCOPE_AGENT) < NBLK) {
            __builtin_amdgcn_s_sleep(2);
        }
    }
    __syncthreads();

    // ================= PHASE C: out = Lt^T-style GEMM (proven R4 staging) ===
    {
        const int p = blockIdx.x;
        const int lg = (p & 7) * 32 + (p >> 3);   // bijective XCD swizzle
        const int it = lg & 1, ot = (lg >> 1) & 15, b = lg >> 5;

        // wave w owns global ks slots [w*16, w*16+16)
        const u16* aG = Lt + (((size_t)ot * 128 + w * 16) * 64 + l) * 8;
        const u16* bG = Vt + (((size_t)(b * 2 + it) * 128 + w * 16) * 64 + l) * 8;

        v16f acc0 = {0,0,0,0,0,0,0,0,0,0,0,0,0,0,0,0};
        v16f acc1 = acc0;

#define STAGE(c, buf)                                                           \
    {                                                                           \
        _Pragma("unroll")                                                       \
        for (int ksl = 0; ksl < 4; ++ksl) {                                     \
            gload16(aG + ((c) * 4 + ksl) * 512, &S.g.LB[w][buf][0][ksl * 512]); \
            gload16(bG + ((c) * 4 + ksl) * 512, &S.g.LB[w][buf][1][ksl * 512]); \
        }                                                                       \
    }

        STAGE(0, 0);
        STAGE(1, 1);
        #pragma unroll
        for (int c = 0; c < 4; ++c) {
            if (c < 3) { asm volatile("s_waitcnt vmcnt(8)" ::: "memory"); }
            else       { asm volatile("s_waitcnt vmcnt(0)" ::: "memory"); }
            __builtin_amdgcn_sched_barrier(0);
            const int buf = c & 1;
            #pragma unroll
            for (int ksl = 0; ksl < 4; ++ksl) {
                s16x8 A = *(const s16x8*)&S.g.LB[w][buf][0][ksl * 512 + l * 8];
                s16x8 B = *(const s16x8*)&S.g.LB[w][buf][1][ksl * 512 + l * 8];
                if (ksl & 1) acc1 = __builtin_amdgcn_mfma_f32_32x32x16_bf16(A, B, acc1, 0, 0, 0);
                else         acc0 = __builtin_amdgcn_mfma_f32_32x32x16_bf16(A, B, acc0, 0, 0, 0);
            }
            asm volatile("s_waitcnt lgkmcnt(0)" ::: "memory");
            __builtin_amdgcn_sched_barrier(0);
            if (c + 2 < 4) STAGE(c + 2, buf);
        }
#undef STAGE

        // 8-way cross-wave K reduction in LDS, stride 17 = conflict-free
        __syncthreads();
        float* red = (float*)&S.g.LB[0][0][0][0];
        {
            const int base = (w * 64 + l) * 17;
            #pragma unroll
            for (int r = 0; r < 16; ++r) red[base + r] = acc0[r] + acc1[r];
        }
        __syncthreads();
        {
            const int icol = t & 31;
            const int orow0 = t >> 5;          // 0..15
            #pragma unroll
            for (int oq = 0; oq < 2; ++oq) {
                const int orow = orow0 + oq * 16;
                const int hi = (orow >> 2) & 1;
                const int r = (orow & 3) | ((orow >> 3) << 2);
                const int lp = icol + 32 * hi;
                float s = 0.f;
                #pragma unroll
                for (int w8 = 0; w8 < 8; ++w8)
                    s += red[(w8 * 64 + lp) * 17 + r];
                out[((size_t)b * OSQ + ot * 32 + orow) * 64 + it * 32 + icol] = s;
            }
        }
    }
}

extern "C" void kernel_launch(void* const* d_in, const int* in_sizes, int n_in,
                              void* d_out, int out_size, void* d_ws, size_t ws_size,
                              hipStream_t stream) {
    const float* seq   = (const float*)d_in[0];
    const float* Mm    = (const float*)d_in[1];
    const float* P     = (const float*)d_in[2];
    const float* Lnk   = (const float*)d_in[3];
    const float* gamma = (const float*)d_in[4];
    const float* beta  = (const float*)d_in[5];

    u16* Lt  = (u16*)d_ws;                          // 2 MB
    u16* Vt  = (u16*)((char*)d_ws + (2u << 20));    // 2 MB
    u32* cnt = (u32*)((char*)d_ws + (4u << 20));    // 4 B barrier counter

    hipMemsetAsync(cnt, 0, 4, stream);
    kFused<<<NBLK, 512, 0, stream>>>(seq, Mm, P, gamma, beta, Lnk, Lt, Vt, cnt,
                                     (float*)d_out);
}

// Round 8
// 21.667 us; speedup vs baseline: 4.7201x; 4.7201x over previous
//
#include <hip/hip_runtime.h>
#include <math.h>

#define SS 2048
#define OSQ 512
#define GG 5

typedef unsigned short u16;
typedef unsigned int u32;
typedef __attribute__((ext_vector_type(8))) short s16x8;
typedef __attribute__((ext_vector_type(4))) float v4f;
typedef __attribute__((ext_vector_type(16))) float v16f;

__device__ __forceinline__ float rcp_f(float x) {
    float r; asm("v_rcp_f32 %0, %1" : "=v"(r) : "v"(x)); return r;
}
__device__ __forceinline__ float cos_rev(float x) {
    float fr, c;
    asm("v_fract_f32 %0, %1" : "=v"(fr) : "v"(x));
    asm("v_cos_f32 %0, %1" : "=v"(c) : "v"(fr));
    return c;
}
__device__ __forceinline__ float cos01(float x) {
    float c; asm("v_cos_f32 %0, %1" : "=v"(c) : "v"(x)); return c;
}
__device__ __forceinline__ u16 f2bf(float f) {
    u32 u = __float_as_uint(f);
    return (u16)((u + 0x7FFFu + ((u >> 16) & 1u)) >> 16);
}
__device__ __forceinline__ float bf2f(u16 h) {
    return __uint_as_float((u32)h << 16);
}
__device__ __forceinline__ void gload16(const void* g, void* l) {
    __builtin_amdgcn_global_load_lds((const __attribute__((address_space(1))) void*)g,
                                     (__attribute__((address_space(3))) void*)l, 16, 0, 0);
}

// ---------------------------------------------------------------------------
// Fragment layouts (16B per lane-slot, bf16):
//   Lt_frag[(o32blk*128 + ks)*64 + slot] : Linker[k][o],
//       o = o32blk*32 + (slot&31), k = ks*16 + (slot>>5)*8 + {0..7}
//   Vt_frag[((b*2+i32blk)*128 + ks)*64 + slot] : V[b][i][k], same slot rule.
// Exactly the A/B operand fragments of v_mfma_f32_32x32x16_bf16.
// ---------------------------------------------------------------------------

// kF: grid 256 x 512 — ONE dispatch round. Per block (k0 = bid*8):
//   Z0 = seq@M^T (MFMA), LayerNorm, W on-the-fly (cos recurrence),
//   T per-k (MFMA), V = T+Z0 -> Vt fragments; plus this k-slice of Lt
//   (fused emission verified in R7).
__global__ __launch_bounds__(512, 1) void kF(const float* __restrict__ seq,
                                             const float* __restrict__ Mm,
                                             const float* __restrict__ P,
                                             const float* __restrict__ gamma,
                                             const float* __restrict__ beta,
                                             const float* __restrict__ Lnk,
                                             u16* __restrict__ Lt,
                                             u16* __restrict__ Vt) {
    __shared__ __align__(16) u16 SEQb[64 * 64];   // bf16, swizzled by (row&7)
    __shared__ __align__(16) u16 Mb[64 * 64];     // bf16, swizzled by (o&7)
    __shared__ __align__(16) u16 SZb[64 * 64];    // Z bf16, swizzled by batch
    __shared__ float Z0l[64 * 68];                // pre-LN projection, f32
    __shared__ u32 Ta32[8 * 2 * 64 * 5];          // T partials bf16 [kc][h][i][10 u16]

    const int t = threadIdx.x;
    const int l = t & 63;
    const int w = t >> 6;
    const int k0 = blockIdx.x * 8;
    const float kf0 = (float)k0;

    const int h = w >> 2;                 // j-half
    const int i0 = (w & 3) * 16;
    const int i_w = i0 + (l & 15);
    const int jc_w = h * 4 + (l >> 4);    // 8-j chunk 0..7

    float pr[40];
    {
        const float4* P4 = (const float4*)(P + ((size_t)i_w * 64 + jc_w * 8) * 5);
        #pragma unroll
        for (int q = 0; q < 10; ++q) {
            float4 v = P4[q];
            pr[q * 4 + 0] = v.x; pr[q * 4 + 1] = v.y; pr[q * 4 + 2] = v.z; pr[q * 4 + 3] = v.w;
        }
    }

    // Lt source loads: issue early, consume at end (hidden under trans init).
    float lnv[8];
    #pragma unroll
    for (int j = 0; j < 8; ++j)
        lnv[j] = Lnk[(size_t)(k0 + j) * OSQ + t];

    // stage seq, M as bf16 (swizzled)
    {
        int row = t >> 3, ch = t & 7;
        int b = row >> 3, kq = row & 7;
        const float* sp = &seq[((size_t)b * SS + k0 + kq) * 64 + ch * 8];
        float4 a = *(const float4*)sp, bb4 = *(const float4*)(sp + 4);
        uint4 pk;
        pk.x = (u32)f2bf(a.x) | ((u32)f2bf(a.y) << 16);
        pk.y = (u32)f2bf(a.z) | ((u32)f2bf(a.w) << 16);
        pk.z = (u32)f2bf(bb4.x) | ((u32)f2bf(bb4.y) << 16);
        pk.w = (u32)f2bf(bb4.z) | ((u32)f2bf(bb4.w) << 16);
        *(uint4*)&SEQb[row * 64 + ((ch ^ (row & 7)) * 8)] = pk;

        const float* mp = &Mm[(size_t)row * 64 + ch * 8];
        float4 c = *(const float4*)mp, d = *(const float4*)(mp + 4);
        uint4 pm;
        pm.x = (u32)f2bf(c.x) | ((u32)f2bf(c.y) << 16);
        pm.y = (u32)f2bf(c.z) | ((u32)f2bf(c.w) << 16);
        pm.z = (u32)f2bf(d.x) | ((u32)f2bf(d.y) << 16);
        pm.w = (u32)f2bf(d.z) | ((u32)f2bf(d.w) << 16);
        *(uint4*)&Mb[row * 64 + ((ch ^ (row & 7)) * 8)] = pm;
    }

    // cosine recurrence init (trans pipe; overlaps staging + Lnk loads)
    float c0[40], c1[40], t2c[40];
    #pragma unroll
    for (int m = 0; m < 8; ++m) {
        #pragma unroll
        for (int g = 0; g < GG; ++g) {
            int idx = m * 5 + g;
            float pf = (float)((i_w * 64 + jc_w * 8 + m) * 5 + g + 2);
            float inv = rcp_f(pf);
            c0[idx] = cos_rev(kf0 * inv);
            c1[idx] = cos_rev((kf0 + 1.0f) * inv);
            float ct = cos01(inv);
            t2c[idx] = ct + ct;
        }
    }

    float gm[8], bt[8];
    {
        int oc = t & 7;
        float4 a = *(const float4*)&gamma[oc * 8], b = *(const float4*)&gamma[oc * 8 + 4];
        float4 c = *(const float4*)&beta[oc * 8],  d = *(const float4*)&beta[oc * 8 + 4];
        gm[0]=a.x; gm[1]=a.y; gm[2]=a.z; gm[3]=a.w; gm[4]=b.x; gm[5]=b.y; gm[6]=b.z; gm[7]=b.w;
        bt[0]=c.x; bt[1]=c.y; bt[2]=c.z; bt[3]=c.w; bt[4]=d.x; bt[5]=d.y; bt[6]=d.z; bt[7]=d.w;
    }
    __syncthreads();

    // phase 1: Z0 = seq @ M^T via mfma_32x32x16 (waves 0-3)
    if (w < 4) {
        const int qr = w & 1, qc = w >> 1;
        v16f acc = {0,0,0,0,0,0,0,0,0,0,0,0,0,0,0,0};
        const int rowA = qr * 32 + (l & 31);
        const int rowB = qc * 32 + (l & 31);
        #pragma unroll
        for (int ks = 0; ks < 4; ++ks) {
            int cA = (ks * 2 + (l >> 5)) ^ (rowA & 7);
            int cB = (ks * 2 + (l >> 5)) ^ (rowB & 7);
            s16x8 af = *(const s16x8*)&SEQb[rowA * 64 + cA * 8];
            s16x8 bf = *(const s16x8*)&Mb[rowB * 64 + cB * 8];
            acc = __builtin_amdgcn_mfma_f32_32x32x16_bf16(af, bf, acc, 0, 0, 0);
        }
        #pragma unroll
        for (int q = 0; q < 16; ++q) {
            int row = qr * 32 + (q & 3) + 8 * (q >> 2) + 4 * (l >> 5);
            int col = qc * 32 + (l & 31);
            Z0l[row * 68 + col] = acc[q];
        }
    }
    __syncthreads();

    // LayerNorm -> SZb bf16
    {
        const int rI = t >> 3, oc = t & 7;
        float z0v[8];
        float4 a = *(const float4*)&Z0l[rI * 68 + oc * 8];
        float4 b = *(const float4*)&Z0l[rI * 68 + oc * 8 + 4];
        z0v[0]=a.x; z0v[1]=a.y; z0v[2]=a.z; z0v[3]=a.w; z0v[4]=b.x; z0v[5]=b.y; z0v[6]=b.z; z0v[7]=b.w;
        float s1 = ((z0v[0]+z0v[1])+(z0v[2]+z0v[3])) + ((z0v[4]+z0v[5])+(z0v[6]+z0v[7]));
        s1 += __shfl_xor(s1, 1); s1 += __shfl_xor(s1, 2); s1 += __shfl_xor(s1, 4);
        float mu = s1 * 0.015625f;
        float sq = 0.f;
        #pragma unroll
        for (int m = 0; m < 8; ++m) { float dv = z0v[m] - mu; sq = fmaf(dv, dv, sq); }
        sq += __shfl_xor(sq, 1); sq += __shfl_xor(sq, 2); sq += __shfl_xor(sq, 4);
        float rstd = rsqrtf(sq * 0.015625f + 1e-5f);
        u16 zb[8];
        #pragma unroll
        for (int m = 0; m < 8; ++m)
            zb[m] = f2bf(fmaf((z0v[m] - mu) * rstd, gm[m], bt[m]));
        uint4 pk;
        pk.x = (u32)zb[0] | ((u32)zb[1] << 16);
        pk.y = (u32)zb[2] | ((u32)zb[3] << 16);
        pk.z = (u32)zb[4] | ((u32)zb[5] << 16);
        pk.w = (u32)zb[6] | ((u32)zb[7] << 16);
        int slot = oc ^ ((rI >> 3) & 7);
        *(uint4*)&SZb[rI * 64 + slot * 8] = pk;
    }
    __syncthreads();

    // phase 2: all 8 kc, no barriers (waves write disjoint Ta slices)
    const int bcl = l & 7;
    #pragma unroll
    for (int kc = 0; kc < 8; ++kc) {
        if (kc >= 2) {
            #pragma unroll
            for (int x = 0; x < 40; ++x) {
                float cn = fmaf(t2c[x], c1[x], -c0[x]);
                c0[x] = c1[x]; c1[x] = cn;
            }
        }
        s16x8 bw;
        #pragma unroll
        for (int j = 0; j < 8; ++j) {
            float a = 0.f;
            #pragma unroll
            for (int g = 0; g < GG; ++g) {
                float ph = (kc == 0) ? c0[j * 5 + g] : c1[j * 5 + g];
                a = fmaf(pr[j * 5 + g], ph, a);
            }
            bw[j] = (short)f2bf(a);
        }
        int arow = bcl * 8 + kc;
        int slot = (h * 4 + (l >> 4)) ^ bcl;
        s16x8 az = *(const s16x8*)&SZb[arow * 64 + slot * 8];
        v4f zc = {0.f, 0.f, 0.f, 0.f};
        v4f d = __builtin_amdgcn_mfma_f32_16x16x32_bf16(az, bw, zc, 0, 0, 0);
        if (l < 32) {
            int ii = i0 + (l & 15);
            int bb2 = (l >> 4) * 2;
            u32 base = (u32)((kc * 2 + h) * 64 + ii) * 5 + bb2;
            Ta32[base]     = (u32)f2bf(d[0]) | ((u32)f2bf(d[1]) << 16);
            Ta32[base + 1] = (u32)f2bf(d[2]) | ((u32)f2bf(d[3]) << 16);
        }
    }
    __syncthreads();

    // assembly: thread (w=b, l=i): V = T(h0)+T(h1)+Z0, write Vt fragment
    {
        const u16* TaR = (const u16*)Ta32;
        float vk[8];
        #pragma unroll
        for (int kc = 0; kc < 8; ++kc)
            vk[kc] = bf2f(TaR[((kc * 2 + 0) * 64 + l) * 10 + w])
                   + bf2f(TaR[((kc * 2 + 1) * 64 + l) * 10 + w])
                   + Z0l[(w * 8 + kc) * 68 + l];
        uint4 pk;
        pk.x = (u32)f2bf(vk[0]) | ((u32)f2bf(vk[1]) << 16);
        pk.y = (u32)f2bf(vk[2]) | ((u32)f2bf(vk[3]) << 16);
        pk.z = (u32)f2bf(vk[4]) | ((u32)f2bf(vk[5]) << 16);
        pk.w = (u32)f2bf(vk[6]) | ((u32)f2bf(vk[7]) << 16);
        const int ks = k0 >> 4;
        const int hi = (k0 >> 3) & 1;
        size_t idx16 = ((size_t)(w * 2 + (l >> 5)) * 128 + ks) * 64 + (l & 31) + 32 * hi;
        *(uint4*)&Vt[idx16 * 8] = pk;
    }

    // Lt emission (this block's k-slice, all 512 threads; og = t) [R7-verified]
    {
        uint4 pk;
        pk.x = (u32)f2bf(lnv[0]) | ((u32)f2bf(lnv[1]) << 16);
        pk.y = (u32)f2bf(lnv[2]) | ((u32)f2bf(lnv[3]) << 16);
        pk.z = (u32)f2bf(lnv[4]) | ((u32)f2bf(lnv[5]) << 16);
        pk.w = (u32)f2bf(lnv[6]) | ((u32)f2bf(lnv[7]) << 16);
        const int ks = k0 >> 4;
        const int hi = (k0 >> 3) & 1;
        size_t idx16 = ((size_t)(t >> 5) * 128 + ks) * 64 + (t & 31) + 32 * hi;
        *(uint4*)&Lt[idx16 * 8] = pk;
    }
}

// ---------------------------------------------------------------------------
// kB2 (R4-proven): out[b][o][i] direct. Grid 256 XCD-swizzled; block =
// 32o x 32i over full K=2048; 4 waves split K (512 each); double-buffered
// global_load_lds with counted vmcnt; LDS reduce; coalesced store.
// ---------------------------------------------------------------------------
__global__ __launch_bounds__(256, 2) void kB2(const u16* __restrict__ Lt,
                                              const u16* __restrict__ Vt,
                                              float* __restrict__ out) {
    __shared__ __align__(16) u16 LB[4][2][2][2048];  // [wave][buf][A/B] 4KB each
    const int t = threadIdx.x;
    const int l = t & 63, w = t >> 6;
    const int p = blockIdx.x;
    const int lg = (p & 7) * 32 + (p >> 3);   // bijective XCD swizzle (256%8==0)
    const int it = lg & 1, ot = (lg >> 1) & 15, b = lg >> 5;

    const u16* aG = Lt + (((size_t)ot * 128 + w * 32) * 64 + l) * 8;
    const u16* bG = Vt + (((size_t)(b * 2 + it) * 128 + w * 32) * 64 + l) * 8;

    v16f acc0 = {0,0,0,0,0,0,0,0,0,0,0,0,0,0,0,0};
    v16f acc1 = acc0;

#define STAGE(c, buf)                                                          \
    {                                                                          \
        _Pragma("unroll")                                                      \
        for (int ksl = 0; ksl < 4; ++ksl) {                                    \
            gload16(aG + ((c) * 4 + ksl) * 512, &LB[w][buf][0][ksl * 512]);    \
            gload16(bG + ((c) * 4 + ksl) * 512, &LB[w][buf][1][ksl * 512]);    \
        }                                                                      \
    }

    STAGE(0, 0);
    STAGE(1, 1);
    #pragma unroll
    for (int c = 0; c < 8; ++c) {
        if (c < 7) { asm volatile("s_waitcnt vmcnt(8)" ::: "memory"); }
        else       { asm volatile("s_waitcnt vmcnt(0)" ::: "memory"); }
        __builtin_amdgcn_sched_barrier(0);
        const int buf = c & 1;
        #pragma unroll
        for (int ksl = 0; ksl < 4; ++ksl) {
            s16x8 A = *(const s16x8*)&LB[w][buf][0][ksl * 512 + l * 8];
            s16x8 B = *(const s16x8*)&LB[w][buf][1][ksl * 512 + l * 8];
            if (ksl & 1) acc1 = __builtin_amdgcn_mfma_f32_32x32x16_bf16(A, B, acc1, 0, 0, 0);
            else         acc0 = __builtin_amdgcn_mfma_f32_32x32x16_bf16(A, B, acc0, 0, 0, 0);
        }
        asm volatile("s_waitcnt lgkmcnt(0)" ::: "memory");
        __builtin_amdgcn_sched_barrier(0);
        if (c + 2 < 8) STAGE(c + 2, buf);
    }
#undef STAGE

    // cross-wave K reduction in LDS (reuse LB), stride 17 = conflict-free
    __syncthreads();
    float* red = (float*)LB;
    {
        const int base = (w * 64 + l) * 17;
        #pragma unroll
        for (int r = 0; r < 16; ++r) red[base + r] = acc0[r] + acc1[r];
    }
    __syncthreads();
    {
        const int icol = t & 31;
        const int ob = (t >> 5) * 4;
        #pragma unroll
        for (int q = 0; q < 4; ++q) {
            const int orow = ob + q;
            const int hi = (orow >> 2) & 1;
            const int r = (orow & 3) | ((orow >> 3) << 2);
            const int lp = icol + 32 * hi;
            float s = red[(0 * 64 + lp) * 17 + r] + red[(1 * 64 + lp) * 17 + r]
                    + red[(2 * 64 + lp) * 17 + r] + red[(3 * 64 + lp) * 17 + r];
            out[((size_t)b * OSQ + ot * 32 + orow) * 64 + it * 32 + icol] = s;
        }
    }
}

extern "C" void kernel_launch(void* const* d_in, const int* in_sizes, int n_in,
                              void* d_out, int out_size, void* d_ws, size_t ws_size,
                              hipStream_t stream) {
    const float* seq   = (const float*)d_in[0];
    const float* Mm    = (const float*)d_in[1];
    const float* P     = (const float*)d_in[2];
    const float* Lnk   = (const float*)d_in[3];
    const float* gamma = (const float*)d_in[4];
    const float* beta  = (const float*)d_in[5];

    u16* Lt = (u16*)d_ws;                          // 512*2048 bf16 = 2 MB
    u16* Vt = (u16*)((char*)d_ws + (2u << 20));    // 8*64*2048 bf16 = 2 MB

    kF<<<256, 512, 0, stream>>>(seq, Mm, P, gamma, beta, Lnk, Lt, Vt);
    kB2<<<256, 256, 0, stream>>>(Lt, Vt, (float*)d_out);
}